// Round 3
// baseline (688.203 us; speedup 1.0000x reference)
//
#include <hip/hip_runtime.h>

typedef __bf16 bf16;
typedef __attribute__((ext_vector_type(8))) __bf16 bf16x8;
typedef __attribute__((ext_vector_type(4))) float f32x4;

typedef __attribute__((address_space(1))) void gvoid_t;
typedef __attribute__((address_space(3))) void lvoid_t;

#define LDS_LOAD16(gp, lp) \
    __builtin_amdgcn_global_load_lds((gvoid_t*)(gp), (lvoid_t*)(lp), 16, 0, 0)

// ---------------------------------------------------------------------------
// fp32 -> bf16 conversion, 8 elems/thread (two float4 loads, one 16B store).
// ---------------------------------------------------------------------------
__global__ __launch_bounds__(256)
void f32_to_bf16(const float* __restrict__ in, bf16* __restrict__ out, int n8)
{
    const int i = blockIdx.x * 256 + threadIdx.x;
    if (i >= n8) return;
    const float4 a = ((const float4*)in)[i * 2];
    const float4 b = ((const float4*)in)[i * 2 + 1];
    bf16x8 o;
    o[0] = (bf16)a.x; o[1] = (bf16)a.y; o[2] = (bf16)a.z; o[3] = (bf16)a.w;
    o[4] = (bf16)b.x; o[5] = (bf16)b.y; o[6] = (bf16)b.z; o[7] = (bf16)b.w;
    *(bf16x8*)(out + (size_t)i * 8) = o;
}

// ---------------------------------------------------------------------------
// C[m][n] = A[m][K] * B[n][K]^T (+ bias[n] if BIAS). bf16 in, fp32 accum,
// CT out (bf16 or float). m97-style: 128x128 tile, BK=32, global_load_lds.
// Grid covers (n: blockIdx.x*128, m: blockIdx.y*128); C row stride = ldc.
// ---------------------------------------------------------------------------
template <int BIAS, typename CT>
__global__ __launch_bounds__(256, 2)
void gemm_bt(const bf16* __restrict__ A, const bf16* __restrict__ B,
             const float* __restrict__ bias, CT* __restrict__ C,
             int K, int ldc)
{
    __shared__ bf16 sA[128 * 32];
    __shared__ bf16 sB[128 * 32];
    const int tid  = threadIdx.x;
    const int lane = tid & 63;
    const int wid  = tid >> 6;
    const int m0 = blockIdx.y * 128;
    const int n0 = blockIdx.x * 128;
    const int wm = (wid >> 1) * 64;
    const int wn = (wid & 1) * 64;
    const int l15   = lane & 15;
    const int quad8 = (lane >> 4) * 8;

    f32x4 acc[4][4] = {};

    for (int k0 = 0; k0 < K; k0 += 32) {
#pragma unroll
        for (int t = 0; t < 2; ++t) {
            const int e  = (t * 4 + wid) * 512;   // wave-uniform LDS chunk base (elems)
            const int ge = e + lane * 8;
            const int r = ge >> 5, c = ge & 31;
            LDS_LOAD16(A + (size_t)(m0 + r) * K + k0 + c, sA + e);
            LDS_LOAD16(B + (size_t)(n0 + r) * K + k0 + c, sB + e);
        }
        __syncthreads();

        bf16x8 af[4], bfr[4];
#pragma unroll
        for (int i = 0; i < 4; ++i) {
            af[i]  = *(const bf16x8*)(sA + (wm + i * 16 + l15) * 32 + quad8);
            bfr[i] = *(const bf16x8*)(sB + (wn + i * 16 + l15) * 32 + quad8);
        }
#pragma unroll
        for (int i = 0; i < 4; ++i)
#pragma unroll
            for (int j = 0; j < 4; ++j)
                acc[i][j] = __builtin_amdgcn_mfma_f32_16x16x32_bf16(af[i], bfr[j], acc[i][j], 0, 0, 0);
        __syncthreads();
    }

    const int rowBase = m0 + wm + (lane >> 4) * 4;
    const int colBase = n0 + wn + l15;
#pragma unroll
    for (int j = 0; j < 4; ++j) {
        const int col = colBase + j * 16;
        const float bv = BIAS ? bias[col] : 0.0f;
#pragma unroll
        for (int i = 0; i < 4; ++i) {
            const int row = rowBase + i * 16;
#pragma unroll
            for (int r = 0; r < 4; ++r)
                C[(size_t)(row + r) * ldc + col] = (CT)(acc[i][j][r] + bv);
        }
    }
}

// ---------------------------------------------------------------------------
// QKNorm (fp32 RMS over head_dim=128) + RoPE + rearrange.
//  qkv [L][9216] bf16 -> Qh/Kh [24][2048][128] (normed+roped), Vt [24][128][2048].
// One wave per (h, l), h-major so Vt scatter writes combine in L2.
// pe / q_scale / k_scale are fp32.
// ---------------------------------------------------------------------------
__global__ __launch_bounds__(256)
void qk_rope_rearrange(const bf16* __restrict__ qkv, const float* __restrict__ pe,
                       const float* __restrict__ qs, const float* __restrict__ ks,
                       bf16* __restrict__ Qh, bf16* __restrict__ Kh, bf16* __restrict__ Vt)
{
    const int lane = threadIdx.x & 63;
    const int wid  = threadIdx.x >> 6;
    const int idx  = blockIdx.x * 4 + wid;     // = h*2048 + l
    const int h = idx >> 11;
    const int l = idx & 2047;

    const size_t rowb = (size_t)l * 9216 + h * 128 + 2 * lane;
    const float q0 = (float)qkv[rowb];
    const float q1 = (float)qkv[rowb + 1];
    const float k0 = (float)qkv[rowb + 3072];
    const float k1 = (float)qkv[rowb + 3073];
    const bf16  v0 = qkv[rowb + 6144];
    const bf16  v1 = qkv[rowb + 6145];

    float ssq = q0 * q0 + q1 * q1;
    float ssk = k0 * k0 + k1 * k1;
#pragma unroll
    for (int off = 1; off < 64; off <<= 1) {
        ssq += __shfl_xor(ssq, off);
        ssk += __shfl_xor(ssk, off);
    }
    const float rq = rsqrtf(ssq * (1.0f / 128.0f) + 1e-6f);
    const float rk = rsqrtf(ssk * (1.0f / 128.0f) + 1e-6f);

    const float s0q = qs[2 * lane], s1q = qs[2 * lane + 1];
    const float s0k = ks[2 * lane], s1k = ks[2 * lane + 1];

    const float qn0 = (q0 * rq) * s0q;
    const float qn1 = (q1 * rq) * s1q;
    const float kn0 = (k0 * rk) * s0k;
    const float kn1 = (k1 * rk) * s1k;

    // pe[l][i=lane][j][c], flat offset ((l*64+i)*2+j)*2+c
    const float* pp = pe + ((size_t)l * 64 + lane) * 4;
    const float p00 = pp[0], p01 = pp[1];
    const float p10 = pp[2], p11 = pp[3];

    const bf16 qo0 = (bf16)(p00 * qn0 + p01 * qn1);
    const bf16 qo1 = (bf16)(p10 * qn0 + p11 * qn1);
    const bf16 ko0 = (bf16)(p00 * kn0 + p01 * kn1);
    const bf16 ko1 = (bf16)(p10 * kn0 + p11 * kn1);

    const size_t ob = ((size_t)h * 2048 + l) * 128 + 2 * lane;
    Qh[ob] = qo0; Qh[ob + 1] = qo1;
    Kh[ob] = ko0; Kh[ob + 1] = ko1;

    const size_t vb = ((size_t)h * 128 + 2 * lane) * 2048 + l;
    Vt[vb]        = v0;
    Vt[vb + 2048] = v1;
}

// ---------------------------------------------------------------------------
// Flash attention. Block = 4 waves; wave owns 16 q rows; block = 64 q rows.
// Per 64-kv step: S = Q*K^T (16 MFMA), online softmax (per C-layout row,
// 16-lane shfl reductions), P -> LDS (C-layout -> A-layout), PV (16 MFMA).
// LDS rows padded so ds_read_b128 stays at 2-way bank aliasing (free, m136).
// ---------------------------------------------------------------------------
__global__ __launch_bounds__(256, 2)
void flash_attn(const bf16* __restrict__ Qh, const bf16* __restrict__ Kh,
                const bf16* __restrict__ Vt, bf16* __restrict__ AO)
{
    __shared__ bf16 sK[64 * 136];    // [kv][d],  stride 136
    __shared__ bf16 sV[128 * 72];    // [d][kv],  stride 72
    __shared__ bf16 sP[4 * 16 * 72]; // per-wave [q][kv], stride 72

    const int tid   = threadIdx.x;
    const int lane  = tid & 63;
    const int wid   = tid >> 6;
    const int h     = blockIdx.y;
    const int qw    = blockIdx.x * 64 + wid * 16;
    const int l15   = lane & 15;
    const int quad8 = (lane >> 4) * 8;

    bf16x8 aq[4];
    {
        const bf16* qp = Qh + ((size_t)h * 2048 + qw + l15) * 128 + quad8;
#pragma unroll
        for (int ki = 0; ki < 4; ++ki) aq[ki] = *(const bf16x8*)(qp + ki * 32);
    }

    f32x4 o[8] = {};
    float m_i[4], l_i[4];
#pragma unroll
    for (int r = 0; r < 4; ++r) { m_i[r] = -1e30f; l_i[r] = 0.0f; }

    bf16* sPw = sP + wid * (16 * 72);

    for (int kv0 = 0; kv0 < 2048; kv0 += 64) {
#pragma unroll
        for (int i = 0; i < 4; ++i) {
            const int idx = i * 256 + tid;
            {
                const int row = idx >> 4, col = (idx & 15) * 8;
                *(bf16x8*)(sK + row * 136 + col) =
                    *(const bf16x8*)(Kh + ((size_t)h * 2048 + kv0 + row) * 128 + col);
            }
            {
                const int row = idx >> 3, col = (idx & 7) * 8;
                *(bf16x8*)(sV + row * 72 + col) =
                    *(const bf16x8*)(Vt + ((size_t)h * 128 + row) * 2048 + kv0 + col);
            }
        }
        __syncthreads();

        f32x4 s[4];
#pragma unroll
        for (int nt = 0; nt < 4; ++nt) {
            f32x4 t = {};
#pragma unroll
            for (int ki = 0; ki < 4; ++ki) {
                bf16x8 bk = *(const bf16x8*)(sK + (nt * 16 + l15) * 136 + ki * 32 + quad8);
                t = __builtin_amdgcn_mfma_f32_16x16x32_bf16(aq[ki], bk, t, 0, 0, 0);
            }
            s[nt] = t;
        }

#pragma unroll
        for (int r = 0; r < 4; ++r) {
            const float sc = 0.08838834764831845f;   // 1/sqrt(128)
            float v0 = s[0][r] * sc, v1 = s[1][r] * sc;
            float v2 = s[2][r] * sc, v3 = s[3][r] * sc;
            float mx = fmaxf(fmaxf(v0, v1), fmaxf(v2, v3));
#pragma unroll
            for (int off = 1; off < 16; off <<= 1) mx = fmaxf(mx, __shfl_xor(mx, off));
            const float nm    = fmaxf(m_i[r], mx);
            const float alpha = __expf(m_i[r] - nm);
            const float p0 = __expf(v0 - nm);
            const float p1 = __expf(v1 - nm);
            const float p2 = __expf(v2 - nm);
            const float p3 = __expf(v3 - nm);
            float rs = p0 + p1 + p2 + p3;
#pragma unroll
            for (int off = 1; off < 16; off <<= 1) rs += __shfl_xor(rs, off);
            l_i[r] = l_i[r] * alpha + rs;
            m_i[r] = nm;
#pragma unroll
            for (int dt = 0; dt < 8; ++dt) o[dt][r] *= alpha;
            bf16* pw = sPw + ((lane >> 4) * 4 + r) * 72 + l15;
            pw[0]  = (bf16)p0;
            pw[16] = (bf16)p1;
            pw[32] = (bf16)p2;
            pw[48] = (bf16)p3;
        }

#pragma unroll
        for (int kk = 0; kk < 2; ++kk) {
            bf16x8 pa = *(const bf16x8*)(sPw + l15 * 72 + kk * 32 + quad8);
#pragma unroll
            for (int dt = 0; dt < 8; ++dt) {
                bf16x8 bv = *(const bf16x8*)(sV + (dt * 16 + l15) * 72 + kk * 32 + quad8);
                o[dt] = __builtin_amdgcn_mfma_f32_16x16x32_bf16(pa, bv, o[dt], 0, 0, 0);
            }
        }
        __syncthreads();
    }

#pragma unroll
    for (int r = 0; r < 4; ++r) {
        const float inv = 1.0f / l_i[r];
        const size_t row = qw + (lane >> 4) * 4 + r;
        bf16* op = AO + row * 3072 + h * 128 + l15;
#pragma unroll
        for (int dt = 0; dt < 8; ++dt) op[dt * 16] = (bf16)(o[dt][r] * inv);
    }
}

// ---------------------------------------------------------------------------
extern "C" void kernel_launch(void* const* d_in, const int* in_sizes, int n_in,
                              void* d_out, int out_size, void* d_ws, size_t ws_size,
                              hipStream_t stream)
{
    (void)in_sizes; (void)n_in; (void)out_size; (void)ws_size;

    const float* x      = (const float*)d_in[0];
    const float* pe     = (const float*)d_in[1];
    const float* w_qkv  = (const float*)d_in[2];
    const float* w_proj = (const float*)d_in[3];
    const float* b_proj = (const float*)d_in[4];
    const float* q_s    = (const float*)d_in[5];
    const float* k_s    = (const float*)d_in[6];
    float* out = (float*)d_out;

    // workspace layout (bf16 elems), peak 78 MiB, heavy aliasing:
    bf16* xb  = (bf16*)d_ws;                   //  6291456  x as bf16
    bf16* wb  = xb + (size_t)6291456;          //  9437184  per-chunk w_qkv bf16
    bf16* qkv = wb + (size_t)9437184;          // 18874368  [2048][9216]
    bf16* Vt  = qkv + (size_t)18874368;        //  6291456  [24][128][2048]
    bf16* Qh  = xb;                            // alias: xb dead after QKV GEMM
    bf16* Kh  = wb;                            // alias: wb dead after QKV GEMM
    bf16* wpb = qkv;                           // alias: qkv dead after rearrange
    bf16* AO  = qkv + (size_t)9437184;         // alias: fits in qkv region

    f32_to_bf16<<<dim3(3072), 256, 0, stream>>>(x, xb, 786432);
    for (int c = 0; c < 3; ++c) {
        f32_to_bf16<<<dim3(4608), 256, 0, stream>>>(w_qkv + (size_t)c * 9437184, wb, 1179648);
        gemm_bt<0, bf16><<<dim3(24, 16), 256, 0, stream>>>(xb, wb, nullptr, qkv + c * 3072, 3072, 9216);
    }
    qk_rope_rearrange<<<dim3(12288), 256, 0, stream>>>(qkv, pe, q_s, k_s, Qh, Kh, Vt);
    f32_to_bf16<<<dim3(4608), 256, 0, stream>>>(w_proj, wpb, 1179648);
    flash_attn<<<dim3(32, 24), 256, 0, stream>>>(Qh, Kh, Vt, AO);
    gemm_bt<1, float><<<dim3(24, 16), 256, 0, stream>>>(AO, wpb, b_proj, out, 3072, 3072);
}

// Round 4
// 680.334 us; speedup vs baseline: 1.0116x; 1.0116x over previous
//
#include <hip/hip_runtime.h>

typedef __bf16 bf16;
typedef __attribute__((ext_vector_type(8))) __bf16 bf16x8;
typedef __attribute__((ext_vector_type(4))) float f32x4;

typedef __attribute__((address_space(1))) void gvoid_t;
typedef __attribute__((address_space(3))) void lvoid_t;

#define LDS_LOAD16(gp, lp) \
    __builtin_amdgcn_global_load_lds((gvoid_t*)(gp), (lvoid_t*)(lp), 16, 0, 0)

// ---------------------------------------------------------------------------
// fp32 -> bf16 conversion, 8 elems/thread (two float4 loads, one 16B store).
// ---------------------------------------------------------------------------
__global__ __launch_bounds__(256)
void f32_to_bf16(const float* __restrict__ in, bf16* __restrict__ out, int n8)
{
    const int i = blockIdx.x * 256 + threadIdx.x;
    if (i >= n8) return;
    const float4 a = ((const float4*)in)[i * 2];
    const float4 b = ((const float4*)in)[i * 2 + 1];
    bf16x8 o;
    o[0] = (bf16)a.x; o[1] = (bf16)a.y; o[2] = (bf16)a.z; o[3] = (bf16)a.w;
    o[4] = (bf16)b.x; o[5] = (bf16)b.y; o[6] = (bf16)b.z; o[7] = (bf16)b.w;
    *(bf16x8*)(out + (size_t)i * 8) = o;
}

// ---------------------------------------------------------------------------
// C[m][n] = A[m][K] * B[n][K]^T (+ bias[n] if BIAS). bf16 in, fp32 accum,
// CT out (bf16 or float). m97-style: 128x128 tile, BK=32, global_load_lds.
// ---------------------------------------------------------------------------
template <int BIAS, typename CT>
__global__ __launch_bounds__(256, 2)
void gemm_bt(const bf16* __restrict__ A, const bf16* __restrict__ B,
             const float* __restrict__ bias, CT* __restrict__ C,
             int K, int ldc)
{
    __shared__ bf16 sA[128 * 32];
    __shared__ bf16 sB[128 * 32];
    const int tid  = threadIdx.x;
    const int lane = tid & 63;
    const int wid  = tid >> 6;
    const int m0 = blockIdx.y * 128;
    const int n0 = blockIdx.x * 128;
    const int wm = (wid >> 1) * 64;
    const int wn = (wid & 1) * 64;
    const int l15   = lane & 15;
    const int quad8 = (lane >> 4) * 8;

    f32x4 acc[4][4] = {};

    for (int k0 = 0; k0 < K; k0 += 32) {
#pragma unroll
        for (int t = 0; t < 2; ++t) {
            const int e  = (t * 4 + wid) * 512;   // wave-uniform LDS chunk base (elems)
            const int ge = e + lane * 8;
            const int r = ge >> 5, c = ge & 31;
            LDS_LOAD16(A + (size_t)(m0 + r) * K + k0 + c, sA + e);
            LDS_LOAD16(B + (size_t)(n0 + r) * K + k0 + c, sB + e);
        }
        __syncthreads();

        bf16x8 af[4], bfr[4];
#pragma unroll
        for (int i = 0; i < 4; ++i) {
            af[i]  = *(const bf16x8*)(sA + (wm + i * 16 + l15) * 32 + quad8);
            bfr[i] = *(const bf16x8*)(sB + (wn + i * 16 + l15) * 32 + quad8);
        }
#pragma unroll
        for (int i = 0; i < 4; ++i)
#pragma unroll
            for (int j = 0; j < 4; ++j)
                acc[i][j] = __builtin_amdgcn_mfma_f32_16x16x32_bf16(af[i], bfr[j], acc[i][j], 0, 0, 0);
        __syncthreads();
    }

    const int rowBase = m0 + wm + (lane >> 4) * 4;
    const int colBase = n0 + wn + l15;
#pragma unroll
    for (int j = 0; j < 4; ++j) {
        const int col = colBase + j * 16;
        const float bv = BIAS ? bias[col] : 0.0f;
#pragma unroll
        for (int i = 0; i < 4; ++i) {
            const int row = rowBase + i * 16;
#pragma unroll
            for (int r = 0; r < 4; ++r)
                C[(size_t)(row + r) * ldc + col] = (CT)(acc[i][j][r] + bv);
        }
    }
}

// ---------------------------------------------------------------------------
// QKNorm (fp32 RMS over head_dim=128) + RoPE + rearrange.
//  qkv [L][9216] bf16 -> Qh/Kh [24][2048][128] (normed+roped), Vt [24][128][2048].
// ---------------------------------------------------------------------------
__global__ __launch_bounds__(256)
void qk_rope_rearrange(const bf16* __restrict__ qkv, const float* __restrict__ pe,
                       const float* __restrict__ qs, const float* __restrict__ ks,
                       bf16* __restrict__ Qh, bf16* __restrict__ Kh, bf16* __restrict__ Vt)
{
    const int lane = threadIdx.x & 63;
    const int wid  = threadIdx.x >> 6;
    const int idx  = blockIdx.x * 4 + wid;     // = h*2048 + l
    const int h = idx >> 11;
    const int l = idx & 2047;

    const size_t rowb = (size_t)l * 9216 + h * 128 + 2 * lane;
    const float q0 = (float)qkv[rowb];
    const float q1 = (float)qkv[rowb + 1];
    const float k0 = (float)qkv[rowb + 3072];
    const float k1 = (float)qkv[rowb + 3073];
    const bf16  v0 = qkv[rowb + 6144];
    const bf16  v1 = qkv[rowb + 6145];

    float ssq = q0 * q0 + q1 * q1;
    float ssk = k0 * k0 + k1 * k1;
#pragma unroll
    for (int off = 1; off < 64; off <<= 1) {
        ssq += __shfl_xor(ssq, off);
        ssk += __shfl_xor(ssk, off);
    }
    const float rq = rsqrtf(ssq * (1.0f / 128.0f) + 1e-6f);
    const float rk = rsqrtf(ssk * (1.0f / 128.0f) + 1e-6f);

    const float s0q = qs[2 * lane], s1q = qs[2 * lane + 1];
    const float s0k = ks[2 * lane], s1k = ks[2 * lane + 1];

    const float qn0 = (q0 * rq) * s0q;
    const float qn1 = (q1 * rq) * s1q;
    const float kn0 = (k0 * rk) * s0k;
    const float kn1 = (k1 * rk) * s1k;

    const float* pp = pe + ((size_t)l * 64 + lane) * 4;
    const float p00 = pp[0], p01 = pp[1];
    const float p10 = pp[2], p11 = pp[3];

    const bf16 qo0 = (bf16)(p00 * qn0 + p01 * qn1);
    const bf16 qo1 = (bf16)(p10 * qn0 + p11 * qn1);
    const bf16 ko0 = (bf16)(p00 * kn0 + p01 * kn1);
    const bf16 ko1 = (bf16)(p10 * kn0 + p11 * kn1);

    const size_t ob = ((size_t)h * 2048 + l) * 128 + 2 * lane;
    Qh[ob] = qo0; Qh[ob + 1] = qo1;
    Kh[ob] = ko0; Kh[ob + 1] = ko1;

    const size_t vb = ((size_t)h * 128 + 2 * lane) * 2048 + l;
    Vt[vb]        = v0;
    Vt[vb + 2048] = v1;
}

// ---------------------------------------------------------------------------
// Flash attention v2. Block = 4 waves x 16 q-rows = 64 q; kv-steps of 64.
//  - K staged via async global_load_lds into XOR-swizzled sK (phys colgroup =
//    logical ^ (row&7)); b128 reads stay 2-way bank-aliased (free, m136).
//  - Double-buffered sK -> ONE barrier per step, DMA overlaps compute.
//  - V B-fragments read directly from global Vt (L2/L1) - no sV.
//  - No-max softmax: p = exp(s/sqrt(d)) directly (scores bounded, fp32-safe);
//    row-sum l via 2 MFMAs against a ones B-fragment (no shuffles at all).
// ---------------------------------------------------------------------------
__global__ __launch_bounds__(256, 2)
void flash_attn(const bf16* __restrict__ Qh, const bf16* __restrict__ Kh,
                const bf16* __restrict__ Vt, bf16* __restrict__ AO)
{
    __shared__ bf16 sK[2 * 64 * 128];  // double-buffered, XOR-swizzled, 32 KB
    __shared__ bf16 sP[4 * 16 * 72];   // per-wave P [q][kv], stride 72

    const int tid   = threadIdx.x;
    const int lane  = tid & 63;
    const int wid   = tid >> 6;
    const int h     = blockIdx.y;
    const int qw    = blockIdx.x * 64 + wid * 16;
    const int l15   = lane & 15;
    const int quad  = lane >> 4;
    const int quad8 = quad * 8;

    const bf16* Kbase = Kh + (size_t)h * 2048 * 128;
    const bf16* Vbase = Vt + (size_t)h * 128 * 2048;

    // Q fragments (A-layout) in registers
    bf16x8 aq[4];
    {
        const bf16* qp = Qh + ((size_t)h * 2048 + qw + l15) * 128 + quad8;
#pragma unroll
        for (int ki = 0; ki < 4; ++ki) aq[ki] = *(const bf16x8*)(qp + ki * 32);
    }

    bf16x8 ones;
#pragma unroll
    for (int i = 0; i < 8; ++i) ones[i] = (bf16)1.0f;

    f32x4 o[8] = {};
    f32x4 lacc = {};

    bf16* sPw = sP + wid * (16 * 72);

    // stage K tile for a kv offset into buffer buf (async DMA)
    const int slotbase = wid * 64;         // per-wave slot base within a 256-slot issue
#define STAGE_K(kv, buf)                                                        \
    {                                                                           \
        bf16* kb = sK + (buf) * (64 * 128);                                     \
        _Pragma("unroll")                                                       \
        for (int t = 0; t < 4; ++t) {                                           \
            const int sb   = t * 256 + slotbase;   /* wave-uniform */           \
            const int slot = sb + lane;                                         \
            const int r    = slot >> 4;                                         \
            const int cg   = (slot & 15) ^ (r & 7);                             \
            LDS_LOAD16(Kbase + (size_t)((kv) + r) * 128 + cg * 8, kb + sb * 8); \
        }                                                                       \
    }

    STAGE_K(0, 0);

    for (int s = 0; s < 32; ++s) {
        __syncthreads();                       // completes stage s; guards buffer reuse
        if (s < 31) STAGE_K((s + 1) * 64, (s + 1) & 1);   // prefetch, overlaps below

        const bf16* kb = sK + (s & 1) * (64 * 128);
        const int kv0 = s * 64;

        // S = Q K^T  (16 MFMA), swizzled sK reads
        f32x4 sc[4];
#pragma unroll
        for (int nt = 0; nt < 4; ++nt) {
            f32x4 t = {};
            const int row = nt * 16 + l15;
#pragma unroll
            for (int ki = 0; ki < 4; ++ki) {
                const int pcg = (4 * ki + quad) ^ (l15 & 7);
                bf16x8 bk = *(const bf16x8*)(kb + row * 128 + pcg * 8);
                t = __builtin_amdgcn_mfma_f32_16x16x32_bf16(aq[ki], bk, t, 0, 0, 0);
            }
            sc[nt] = t;
        }

        // p = exp(s * scale); write P to LDS (C-layout -> A-layout transform)
#pragma unroll
        for (int r = 0; r < 4; ++r) {
            const float scl = 0.08838834764831845f;   // 1/sqrt(128)
            bf16* pw = sPw + (quad * 4 + r) * 72 + l15;
            pw[0]  = (bf16)__expf(sc[0][r] * scl);
            pw[16] = (bf16)__expf(sc[1][r] * scl);
            pw[32] = (bf16)__expf(sc[2][r] * scl);
            pw[48] = (bf16)__expf(sc[3][r] * scl);
        }

        // PV (16 MFMA, V from global) + row-sum l (2 MFMA vs ones)
#pragma unroll
        for (int kk = 0; kk < 2; ++kk) {
            bf16x8 pa = *(const bf16x8*)(sPw + l15 * 72 + kk * 32 + quad8);
            lacc = __builtin_amdgcn_mfma_f32_16x16x32_bf16(pa, ones, lacc, 0, 0, 0);
#pragma unroll
            for (int dt = 0; dt < 8; ++dt) {
                bf16x8 bv = *(const bf16x8*)(Vbase + (size_t)(dt * 16 + l15) * 2048
                                             + kv0 + kk * 32 + quad8);
                o[dt] = __builtin_amdgcn_mfma_f32_16x16x32_bf16(pa, bv, o[dt], 0, 0, 0);
            }
        }
    }
#undef STAGE_K

#pragma unroll
    for (int r = 0; r < 4; ++r) {
        const float inv = 1.0f / lacc[r];
        const size_t row = qw + quad * 4 + r;
        bf16* op = AO + row * 3072 + h * 128 + l15;
#pragma unroll
        for (int dt = 0; dt < 8; ++dt) op[dt * 16] = (bf16)(o[dt][r] * inv);
    }
}

// ---------------------------------------------------------------------------
extern "C" void kernel_launch(void* const* d_in, const int* in_sizes, int n_in,
                              void* d_out, int out_size, void* d_ws, size_t ws_size,
                              hipStream_t stream)
{
    (void)in_sizes; (void)n_in; (void)out_size;

    const float* x      = (const float*)d_in[0];
    const float* pe     = (const float*)d_in[1];
    const float* w_qkv  = (const float*)d_in[2];
    const float* w_proj = (const float*)d_in[3];
    const float* b_proj = (const float*)d_in[4];
    const float* q_s    = (const float*)d_in[5];
    const float* k_s    = (const float*)d_in[6];
    float* out = (float*)d_out;

    const size_t NEED_BIG = ((size_t)6291456 + 28311552 + 18874368 + 6291456) * 2; // 119.5 MB

    if (ws_size >= NEED_BIG) {
        // single-launch QKV path (balanced 1152-block grid)
        bf16* xb  = (bf16*)d_ws;                  //  6291456  x bf16
        bf16* wb  = xb + (size_t)6291456;         // 28311552  w_qkv bf16
        bf16* qkv = wb + (size_t)28311552;        // 18874368  [2048][9216]
        bf16* Vt  = qkv + (size_t)18874368;       //  6291456  [24][128][2048]
        bf16* Qh  = xb;                           // alias after GEMM
        bf16* Kh  = wb;                           // alias after GEMM
        bf16* wpb = qkv;                          // alias after rearrange
        bf16* AO  = qkv + (size_t)9437184;

        f32_to_bf16<<<dim3(3072),  256, 0, stream>>>(x,     xb, 786432);
        f32_to_bf16<<<dim3(13824), 256, 0, stream>>>(w_qkv, wb, 3538944);
        gemm_bt<0, bf16><<<dim3(72, 16), 256, 0, stream>>>(xb, wb, nullptr, qkv, 3072, 9216);
        qk_rope_rearrange<<<dim3(12288), 256, 0, stream>>>(qkv, pe, q_s, k_s, Qh, Kh, Vt);
        f32_to_bf16<<<dim3(4608), 256, 0, stream>>>(w_proj, wpb, 1179648);
        flash_attn<<<dim3(32, 24), 256, 0, stream>>>(Qh, Kh, Vt, AO);
        gemm_bt<1, float><<<dim3(24, 16), 256, 0, stream>>>(AO, wpb, b_proj, out, 3072, 3072);
    } else {
        // chunked fallback (78.6 MB peak), proven in round 3
        bf16* xb  = (bf16*)d_ws;
        bf16* wb  = xb + (size_t)6291456;
        bf16* qkv = wb + (size_t)9437184;
        bf16* Vt  = qkv + (size_t)18874368;
        bf16* Qh  = xb;
        bf16* Kh  = wb;
        bf16* wpb = qkv;
        bf16* AO  = qkv + (size_t)9437184;

        f32_to_bf16<<<dim3(3072), 256, 0, stream>>>(x, xb, 786432);
        for (int c = 0; c < 3; ++c) {
            f32_to_bf16<<<dim3(4608), 256, 0, stream>>>(w_qkv + (size_t)c * 9437184, wb, 1179648);
            gemm_bt<0, bf16><<<dim3(24, 16), 256, 0, stream>>>(xb, wb, nullptr, qkv + c * 3072, 3072, 9216);
        }
        qk_rope_rearrange<<<dim3(12288), 256, 0, stream>>>(qkv, pe, q_s, k_s, Qh, Kh, Vt);
        f32_to_bf16<<<dim3(4608), 256, 0, stream>>>(w_proj, wpb, 1179648);
        flash_attn<<<dim3(32, 24), 256, 0, stream>>>(Qh, Kh, Vt, AO);
        gemm_bt<1, float><<<dim3(24, 16), 256, 0, stream>>>(AO, wpb, b_proj, out, 3072, 3072);
    }
}

// Round 5
// 597.968 us; speedup vs baseline: 1.1509x; 1.1377x over previous
//
#include <hip/hip_runtime.h>

typedef __bf16 bf16;
typedef __attribute__((ext_vector_type(8))) __bf16 bf16x8;
typedef __attribute__((ext_vector_type(4))) float f32x4;

typedef __attribute__((address_space(1))) void gvoid_t;
typedef __attribute__((address_space(3))) void lvoid_t;

#define LDS_LOAD16(gp, lp) \
    __builtin_amdgcn_global_load_lds((gvoid_t*)(gp), (lvoid_t*)(lp), 16, 0, 0)

// ---------------------------------------------------------------------------
// fp32 -> bf16 conversion, 8 elems/thread (two float4 loads, one 16B store).
// ---------------------------------------------------------------------------
__global__ __launch_bounds__(256)
void f32_to_bf16(const float* __restrict__ in, bf16* __restrict__ out, int n8)
{
    const int i = blockIdx.x * 256 + threadIdx.x;
    if (i >= n8) return;
    const float4 a = ((const float4*)in)[i * 2];
    const float4 b = ((const float4*)in)[i * 2 + 1];
    bf16x8 o;
    o[0] = (bf16)a.x; o[1] = (bf16)a.y; o[2] = (bf16)a.z; o[3] = (bf16)a.w;
    o[4] = (bf16)b.x; o[5] = (bf16)b.y; o[6] = (bf16)b.z; o[7] = (bf16)b.w;
    *(bf16x8*)(out + (size_t)i * 8) = o;
}

// ---------------------------------------------------------------------------
// C[m][n] = A[m][K] * B[n][K]^T (+ bias[n] if BIAS). bf16 in, fp32 accum,
// CT out (bf16 or float). m97-style: 128x128 tile, BK=32, global_load_lds.
// ---------------------------------------------------------------------------
template <int BIAS, typename CT>
__global__ __launch_bounds__(256, 2)
void gemm_bt(const bf16* __restrict__ A, const bf16* __restrict__ B,
             const float* __restrict__ bias, CT* __restrict__ C,
             int K, int ldc)
{
    __shared__ bf16 sA[128 * 32];
    __shared__ bf16 sB[128 * 32];
    const int tid  = threadIdx.x;
    const int lane = tid & 63;
    const int wid  = tid >> 6;
    const int m0 = blockIdx.y * 128;
    const int n0 = blockIdx.x * 128;
    const int wm = (wid >> 1) * 64;
    const int wn = (wid & 1) * 64;
    const int l15   = lane & 15;
    const int quad8 = (lane >> 4) * 8;

    f32x4 acc[4][4] = {};

    for (int k0 = 0; k0 < K; k0 += 32) {
#pragma unroll
        for (int t = 0; t < 2; ++t) {
            const int e  = (t * 4 + wid) * 512;   // wave-uniform LDS chunk base (elems)
            const int ge = e + lane * 8;
            const int r = ge >> 5, c = ge & 31;
            LDS_LOAD16(A + (size_t)(m0 + r) * K + k0 + c, sA + e);
            LDS_LOAD16(B + (size_t)(n0 + r) * K + k0 + c, sB + e);
        }
        __syncthreads();

        bf16x8 af[4], bfr[4];
#pragma unroll
        for (int i = 0; i < 4; ++i) {
            af[i]  = *(const bf16x8*)(sA + (wm + i * 16 + l15) * 32 + quad8);
            bfr[i] = *(const bf16x8*)(sB + (wn + i * 16 + l15) * 32 + quad8);
        }
#pragma unroll
        for (int i = 0; i < 4; ++i)
#pragma unroll
            for (int j = 0; j < 4; ++j)
                acc[i][j] = __builtin_amdgcn_mfma_f32_16x16x32_bf16(af[i], bfr[j], acc[i][j], 0, 0, 0);
        __syncthreads();
    }

    const int rowBase = m0 + wm + (lane >> 4) * 4;
    const int colBase = n0 + wn + l15;
#pragma unroll
    for (int j = 0; j < 4; ++j) {
        const int col = colBase + j * 16;
        const float bv = BIAS ? bias[col] : 0.0f;
#pragma unroll
        for (int i = 0; i < 4; ++i) {
            const int row = rowBase + i * 16;
#pragma unroll
            for (int r = 0; r < 4; ++r)
                C[(size_t)(row + r) * ldc + col] = (CT)(acc[i][j][r] + bv);
        }
    }
}

// ---------------------------------------------------------------------------
// QKNorm (fp32 RMS over head_dim=128) + RoPE + rearrange.
//  qkv [L][9216] bf16 -> Qh/Kh [24][2048][128] (normed+roped), Vt [24][128][2048].
// ---------------------------------------------------------------------------
__global__ __launch_bounds__(256)
void qk_rope_rearrange(const bf16* __restrict__ qkv, const float* __restrict__ pe,
                       const float* __restrict__ qs, const float* __restrict__ ks,
                       bf16* __restrict__ Qh, bf16* __restrict__ Kh, bf16* __restrict__ Vt)
{
    const int lane = threadIdx.x & 63;
    const int wid  = threadIdx.x >> 6;
    const int idx  = blockIdx.x * 4 + wid;     // = h*2048 + l
    const int h = idx >> 11;
    const int l = idx & 2047;

    const size_t rowb = (size_t)l * 9216 + h * 128 + 2 * lane;
    const float q0 = (float)qkv[rowb];
    const float q1 = (float)qkv[rowb + 1];
    const float k0 = (float)qkv[rowb + 3072];
    const float k1 = (float)qkv[rowb + 3073];
    const bf16  v0 = qkv[rowb + 6144];
    const bf16  v1 = qkv[rowb + 6145];

    float ssq = q0 * q0 + q1 * q1;
    float ssk = k0 * k0 + k1 * k1;
#pragma unroll
    for (int off = 1; off < 64; off <<= 1) {
        ssq += __shfl_xor(ssq, off);
        ssk += __shfl_xor(ssk, off);
    }
    const float rq = rsqrtf(ssq * (1.0f / 128.0f) + 1e-6f);
    const float rk = rsqrtf(ssk * (1.0f / 128.0f) + 1e-6f);

    const float s0q = qs[2 * lane], s1q = qs[2 * lane + 1];
    const float s0k = ks[2 * lane], s1k = ks[2 * lane + 1];

    const float qn0 = (q0 * rq) * s0q;
    const float qn1 = (q1 * rq) * s1q;
    const float kn0 = (k0 * rk) * s0k;
    const float kn1 = (k1 * rk) * s1k;

    const float* pp = pe + ((size_t)l * 64 + lane) * 4;
    const float p00 = pp[0], p01 = pp[1];
    const float p10 = pp[2], p11 = pp[3];

    const bf16 qo0 = (bf16)(p00 * qn0 + p01 * qn1);
    const bf16 qo1 = (bf16)(p10 * qn0 + p11 * qn1);
    const bf16 ko0 = (bf16)(p00 * kn0 + p01 * kn1);
    const bf16 ko1 = (bf16)(p10 * kn0 + p11 * kn1);

    const size_t ob = ((size_t)h * 2048 + l) * 128 + 2 * lane;
    Qh[ob] = qo0; Qh[ob + 1] = qo1;
    Kh[ob] = ko0; Kh[ob + 1] = ko1;

    const size_t vb = ((size_t)h * 128 + 2 * lane) * 2048 + l;
    Vt[vb]        = v0;
    Vt[vb + 2048] = v1;
}

// ---------------------------------------------------------------------------
// Flash attention v3. Block = 4 waves x 16 q-rows = 64 q; kv-steps of 64.
//  - K AND V staged via async global_load_lds into XOR-swizzled LDS tiles
//    (phys colgroup = logical ^ (row&7)); b128 reads 2-way aliased (free).
//  - Both double-buffered -> ONE barrier per step; DMA for step s+1 issued
//    right after barrier s, overlapping the whole compute phase. Zero global
//    loads inside the compute phase (fixes round-4 V-latency stall).
//  - No-max softmax: p = exp(s/sqrt(d)); row-sum via 2 MFMAs vs ones.
// ---------------------------------------------------------------------------
__global__ __launch_bounds__(256, 2)
void flash_attn(const bf16* __restrict__ Qh, const bf16* __restrict__ Kh,
                const bf16* __restrict__ Vt, bf16* __restrict__ AO)
{
    __shared__ bf16 sK[2 * 64 * 128];  // [kv][d] swizzled, dbuf, 32 KB
    __shared__ bf16 sV[2 * 128 * 64];  // [d][kv] swizzled, dbuf, 32 KB
    __shared__ bf16 sP[4 * 16 * 72];   // per-wave P [q][kv], stride 72

    const int tid   = threadIdx.x;
    const int lane  = tid & 63;
    const int wid   = tid >> 6;
    const int h     = blockIdx.y;
    const int qw    = blockIdx.x * 64 + wid * 16;
    const int l15   = lane & 15;
    const int quad  = lane >> 4;
    const int quad8 = quad * 8;

    const bf16* Kbase = Kh + (size_t)h * 2048 * 128;
    const bf16* Vbase = Vt + (size_t)h * 128 * 2048;

    // Q fragments (A-layout) in registers
    bf16x8 aq[4];
    {
        const bf16* qp = Qh + ((size_t)h * 2048 + qw + l15) * 128 + quad8;
#pragma unroll
        for (int ki = 0; ki < 4; ++ki) aq[ki] = *(const bf16x8*)(qp + ki * 32);
    }

    bf16x8 ones;
#pragma unroll
    for (int i = 0; i < 8; ++i) ones[i] = (bf16)1.0f;

    f32x4 o[8] = {};
    f32x4 lacc = {};

    bf16* sPw = sP + wid * (16 * 72);
    const int slotbase = wid * 64;     // per-wave slot base (wave-uniform)

    // K tile: 64 kv-rows x 128 d. slot -> (r = slot>>4, pcg = slot&15),
    // global colgroup = pcg ^ (r&7)  (8-elem groups; only low 3 bits flip).
#define STAGE_K(kv, buf)                                                         \
    {                                                                            \
        bf16* kb = sK + (buf) * (64 * 128);                                      \
        _Pragma("unroll")                                                        \
        for (int t = 0; t < 4; ++t) {                                            \
            const int sb   = t * 256 + slotbase;                                 \
            const int slot = sb + lane;                                          \
            const int r    = slot >> 4;                                          \
            const int cg   = (slot & 15) ^ (r & 7);                              \
            LDS_LOAD16(Kbase + (size_t)((kv) + r) * 128 + cg * 8, kb + sb * 8);  \
        }                                                                        \
    }
    // V tile: 128 d-rows x 64 kv. slot -> (r = slot>>3, pcg = slot&7),
    // global colgroup = pcg ^ (r&7).
#define STAGE_V(kv, buf)                                                         \
    {                                                                            \
        bf16* vb = sV + (buf) * (128 * 64);                                      \
        _Pragma("unroll")                                                        \
        for (int t = 0; t < 4; ++t) {                                            \
            const int sb   = t * 256 + slotbase;                                 \
            const int slot = sb + lane;                                          \
            const int r    = slot >> 3;                                          \
            const int cg   = (slot & 7) ^ (r & 7);                               \
            LDS_LOAD16(Vbase + (size_t)r * 2048 + (kv) + cg * 8, vb + sb * 8);   \
        }                                                                        \
    }

    STAGE_K(0, 0);
    STAGE_V(0, 0);

    for (int s = 0; s < 32; ++s) {
        __syncthreads();                   // drains DMA for step s, syncs buffers
        if (s < 31) {                      // prefetch step s+1 into the other buffer
            STAGE_K((s + 1) * 64, (s + 1) & 1);
            STAGE_V((s + 1) * 64, (s + 1) & 1);
        }

        const bf16* kb = sK + (s & 1) * (64 * 128);
        const bf16* vb = sV + (s & 1) * (128 * 64);

        // S = Q K^T  (16 MFMA), swizzled sK reads
        f32x4 sc[4];
#pragma unroll
        for (int nt = 0; nt < 4; ++nt) {
            f32x4 t = {};
            const int row = nt * 16 + l15;
#pragma unroll
            for (int ki = 0; ki < 4; ++ki) {
                const int pcg = (4 * ki + quad) ^ (l15 & 7);
                bf16x8 bk = *(const bf16x8*)(kb + row * 128 + pcg * 8);
                t = __builtin_amdgcn_mfma_f32_16x16x32_bf16(aq[ki], bk, t, 0, 0, 0);
            }
            sc[nt] = t;
        }

        // p = exp(s * scale); write P to LDS (C-layout -> A-layout transform)
#pragma unroll
        for (int r = 0; r < 4; ++r) {
            const float scl = 0.08838834764831845f;   // 1/sqrt(128)
            bf16* pw = sPw + (quad * 4 + r) * 72 + l15;
            pw[0]  = (bf16)__expf(sc[0][r] * scl);
            pw[16] = (bf16)__expf(sc[1][r] * scl);
            pw[32] = (bf16)__expf(sc[2][r] * scl);
            pw[48] = (bf16)__expf(sc[3][r] * scl);
        }

        // PV (16 MFMA, V from swizzled sV) + row-sum l (2 MFMA vs ones)
#pragma unroll
        for (int kk = 0; kk < 2; ++kk) {
            bf16x8 pa = *(const bf16x8*)(sPw + l15 * 72 + kk * 32 + quad8);
            lacc = __builtin_amdgcn_mfma_f32_16x16x32_bf16(pa, ones, lacc, 0, 0, 0);
#pragma unroll
            for (int dt = 0; dt < 8; ++dt) {
                const int row = dt * 16 + l15;
                const int pcg = (kk * 4 + quad) ^ (l15 & 7);
                bf16x8 bv = *(const bf16x8*)(vb + row * 64 + pcg * 8);
                o[dt] = __builtin_amdgcn_mfma_f32_16x16x32_bf16(pa, bv, o[dt], 0, 0, 0);
            }
        }
    }
#undef STAGE_K
#undef STAGE_V

#pragma unroll
    for (int r = 0; r < 4; ++r) {
        const float inv = 1.0f / lacc[r];
        const size_t row = qw + quad * 4 + r;
        bf16* op = AO + row * 3072 + h * 128 + l15;
#pragma unroll
        for (int dt = 0; dt < 8; ++dt) op[dt * 16] = (bf16)(o[dt][r] * inv);
    }
}

// ---------------------------------------------------------------------------
extern "C" void kernel_launch(void* const* d_in, const int* in_sizes, int n_in,
                              void* d_out, int out_size, void* d_ws, size_t ws_size,
                              hipStream_t stream)
{
    (void)in_sizes; (void)n_in; (void)out_size;

    const float* x      = (const float*)d_in[0];
    const float* pe     = (const float*)d_in[1];
    const float* w_qkv  = (const float*)d_in[2];
    const float* w_proj = (const float*)d_in[3];
    const float* b_proj = (const float*)d_in[4];
    const float* q_s    = (const float*)d_in[5];
    const float* k_s    = (const float*)d_in[6];
    float* out = (float*)d_out;

    const size_t NEED_BIG = ((size_t)6291456 + 28311552 + 18874368 + 6291456) * 2; // 119.5 MB

    if (ws_size >= NEED_BIG) {
        // single-launch QKV path (balanced 1152-block grid)
        bf16* xb  = (bf16*)d_ws;                  //  6291456  x bf16
        bf16* wb  = xb + (size_t)6291456;         // 28311552  w_qkv bf16
        bf16* qkv = wb + (size_t)28311552;        // 18874368  [2048][9216]
        bf16* Vt  = qkv + (size_t)18874368;       //  6291456  [24][128][2048]
        bf16* Qh  = xb;                           // alias after GEMM
        bf16* Kh  = wb;                           // alias after GEMM
        bf16* wpb = qkv;                          // alias after rearrange
        bf16* AO  = qkv + (size_t)9437184;

        f32_to_bf16<<<dim3(3072),  256, 0, stream>>>(x,     xb, 786432);
        f32_to_bf16<<<dim3(13824), 256, 0, stream>>>(w_qkv, wb, 3538944);
        gemm_bt<0, bf16><<<dim3(72, 16), 256, 0, stream>>>(xb, wb, nullptr, qkv, 3072, 9216);
        qk_rope_rearrange<<<dim3(12288), 256, 0, stream>>>(qkv, pe, q_s, k_s, Qh, Kh, Vt);
        f32_to_bf16<<<dim3(4608), 256, 0, stream>>>(w_proj, wpb, 1179648);
        flash_attn<<<dim3(32, 24), 256, 0, stream>>>(Qh, Kh, Vt, AO);
        gemm_bt<1, float><<<dim3(24, 16), 256, 0, stream>>>(AO, wpb, b_proj, out, 3072, 3072);
    } else {
        // chunked fallback (78.6 MB peak)
        bf16* xb  = (bf16*)d_ws;
        bf16* wb  = xb + (size_t)6291456;
        bf16* qkv = wb + (size_t)9437184;
        bf16* Vt  = qkv + (size_t)18874368;
        bf16* Qh  = xb;
        bf16* Kh  = wb;
        bf16* wpb = qkv;
        bf16* AO  = qkv + (size_t)9437184;

        f32_to_bf16<<<dim3(3072), 256, 0, stream>>>(x, xb, 786432);
        for (int c = 0; c < 3; ++c) {
            f32_to_bf16<<<dim3(4608), 256, 0, stream>>>(w_qkv + (size_t)c * 9437184, wb, 1179648);
            gemm_bt<0, bf16><<<dim3(24, 16), 256, 0, stream>>>(xb, wb, nullptr, qkv + c * 3072, 3072, 9216);
        }
        qk_rope_rearrange<<<dim3(12288), 256, 0, stream>>>(qkv, pe, q_s, k_s, Qh, Kh, Vt);
        f32_to_bf16<<<dim3(4608), 256, 0, stream>>>(w_proj, wpb, 1179648);
        flash_attn<<<dim3(32, 24), 256, 0, stream>>>(Qh, Kh, Vt, AO);
        gemm_bt<1, float><<<dim3(24, 16), 256, 0, stream>>>(AO, wpb, b_proj, out, 3072, 3072);
    }
}